// Round 3
// baseline (1269.333 us; speedup 1.0000x reference)
//
#include <hip/hip_runtime.h>
#include <stdint.h>

#define K_DIM 4096
#define N_DIM 11008
#define M_DIM 8192
#define BM 256
#define BN 256
#define BK 64
#define NSLAB (K_DIM / BK)   // 64
#define ABUF (BM * BK)       // 16384 halves = 32 KiB per buffer
#define BBUF (BN * BK)
#define NWG ((N_DIM / BN) * (M_DIM / BM))   // 43 * 32 = 1376, % 8 == 0

// fallback (round-0 validated) kernel params
#define FBM 128
#define FBK 32
#define FASTRIDE 32
#define FBSTRIDE 40

typedef _Float16 half8  __attribute__((ext_vector_type(8)));
typedef _Float16 half2v __attribute__((ext_vector_type(2)));
typedef float    floatx4 __attribute__((ext_vector_type(4)));

#define WS_NEEDED ((size_t)M_DIM * K_DIM * 2)   // 64 MiB: fp16 copy of x

__device__ __forceinline__ void async_lds16(const void* g, void* l) {
    __builtin_amdgcn_global_load_lds(
        (const __attribute__((address_space(1))) uint32_t*)g,
        (__attribute__((address_space(3))) uint32_t*)l, 16, 0, 0);
}

// ---------------- prepass: x fp32 -> fp16 (lossless; values are fp16-representable) ----
__global__ __launch_bounds__(256) void cvt_a(const float* __restrict__ x,
                                             _Float16* __restrict__ xh) {
    const size_t i = ((size_t)blockIdx.x * 256 + threadIdx.x) * 8;
    const float4 a = *(const float4*)(x + i);
    const float4 b = *(const float4*)(x + i + 4);
    half8 h;
    h[0] = (_Float16)a.x; h[1] = (_Float16)a.y; h[2] = (_Float16)a.z; h[3] = (_Float16)a.w;
    h[4] = (_Float16)b.x; h[5] = (_Float16)b.y; h[6] = (_Float16)b.z; h[7] = (_Float16)b.w;
    *(half8*)(xh + i) = h;
}

// ---------------- main GEMM: 256x256 tile, dbuf LDS, counted vmcnt, lgkm-only barrier --
// A: self-DMA'd per wave (duplicate-DMA idempotence => no cross-wave A publish needed).
// B: in-loop exact ternary dequant (validated v_perm path) -> swizzled ds_write,
//    published by one lgkm-drained s_barrier per slab. vmcnt is NEVER drained to 0
//    in steady state: 8 A-DMAs stay in flight across the barrier (T3/T4).
__global__ __launch_bounds__(512, 2) void ternary_gemm_db(
    const _Float16* __restrict__ xh,   // (M, K) fp16
    const int*   __restrict__ pw,      // (K/16, N) packed 2-bit codes
    const float* __restrict__ scales,  // (K/128, N) fp32 holding fp16 values
    const float* __restrict__ bias,    // (N,) fp32 holding fp16 values
    float*       __restrict__ out)     // (M, N) fp32
{
    __shared__ __align__(16) _Float16 lds_a[2 * ABUF];  // 64 KiB
    __shared__ __align__(16) _Float16 lds_b[2 * BBUF];  // 64 KiB  (total 128 KiB)

    const int tid  = threadIdx.x;
    const int lane = tid & 63;
    const int w    = tid >> 6;

    // XCD-aware bijective swizzle (NWG % 8 == 0)
    const int bid = blockIdx.x;
    const int swz = (bid & 7) * (NWG / 8) + (bid >> 3);
    const int n0 = (swz % (N_DIM / BN)) * BN;
    const int m0 = (swz / (N_DIM / BN)) * BM;

    const int band = (w & 3) * 64;     // wave's own A m-band (waves w and w+4 duplicate)
    const int wn   = (w >> 2) * 128;   // wave's B n-range

    // ---- A DMA source (per-lane, chunk pre-swizzled: chunk_src = (lane&7) ^ (row&7)) ----
    const int arow = lane >> 3;                  // row mod 8
    const int achk = (lane & 7) ^ arow;
    const _Float16* gaBase = xh + (size_t)(m0 + band + arow) * K_DIM + achk * 8;

    // ---- B staging: thread = (col nb, k-dword pair kp) ----
    const int nb = tid >> 1;                     // 0..255
    const int kp = tid & 1;                      // 0..1
    const int* pwp = pw + (size_t)(kp * 2) * N_DIM + n0 + nb;
    const float* scp = scales + n0 + nb;
    const int s7  = nb & 7;
    const int c0a = ((kp * 2 + 0) * 2 + 0) ^ s7;   // swizzled 16B-chunk indices
    const int c0b = ((kp * 2 + 0) * 2 + 1) ^ s7;
    const int c1a = ((kp * 2 + 1) * 2 + 0) ^ s7;
    const int c1b = ((kp * 2 + 1) * 2 + 1) ^ s7;

    floatx4 acc[4][8];
    #pragma unroll
    for (int i = 0; i < 4; ++i)
        #pragma unroll
        for (int j = 0; j < 8; ++j)
            acc[i][j] = floatx4{0.f, 0.f, 0.f, 0.f};

    const int lr = lane & 15;
    const int g  = lane >> 4;
    const int x7 = lr & 7;

    int aoff[4], boff[8];
    #pragma unroll
    for (int mt = 0; mt < 4; ++mt) aoff[mt] = (band + mt * 16 + lr) * BK;
    #pragma unroll
    for (int nt = 0; nt < 8; ++nt) boff[nt] = (wn + nt * 16 + lr) * BK;

    // exact ternary dequant of one packed dword -> 8 dwords of fp16 {-s,0,+s}
    auto permq = [](uint32_t v, uint32_t tmpl, uint32_t* q) {
        #pragma unroll
        for (int j = 0; j < 8; ++j) {
            uint32_t t4 = (v >> (4 * j)) & 0xFu;
            uint32_t sp = (t4 | (t4 << 14)) & 0x00030003u;
            uint32_t sel = ((sp & 0x00010001u) << 1) | ((0x00030003u - sp) << 8);
            q[j] = __builtin_amdgcn_perm(tmpl, tmpl, sel);
        }
    };
    auto stage_b = [&](uint32_t v0, uint32_t v1, float scf, _Float16* rowb) {
        _Float16 sh = (_Float16)scf;               // lossless (value is fp16)
        uint32_t sbits = (uint32_t)__builtin_bit_cast(unsigned short, sh);
        uint32_t tmpl = sbits | (((sbits >> 8) ^ 0x80u) << 24);
        uint32_t q[8];
        permq(v0, tmpl, q);
        *(uint4*)(rowb + c0a * 8) = make_uint4(q[0], q[1], q[2], q[3]);
        *(uint4*)(rowb + c0b * 8) = make_uint4(q[4], q[5], q[6], q[7]);
        permq(v1, tmpl, q);
        *(uint4*)(rowb + c1a * 8) = make_uint4(q[0], q[1], q[2], q[3]);
        *(uint4*)(rowb + c1b * 8) = make_uint4(q[4], q[5], q[6], q[7]);
    };
    auto stage_a = [&](int slab, int buf) {
        const _Float16* gk = gaBase + slab * BK;
        _Float16* dst = lds_a + buf * ABUF + band * BK;
        #pragma unroll
        for (int i = 0; i < 8; ++i)
            async_lds16(gk + (size_t)i * 8 * K_DIM, dst + i * 8 * BK);
    };

    // ---- prologue: slab 0 staged, slab-1 B operands prefetched ----
    uint32_t pv00 = (uint32_t)pwp[0];
    uint32_t pv01 = (uint32_t)pwp[(size_t)1 * N_DIM];
    float    sc0  = scp[0];
    uint32_t pvA0 = (uint32_t)pwp[(size_t)4 * N_DIM];   // slab 1
    uint32_t pvA1 = (uint32_t)pwp[(size_t)5 * N_DIM];
    float    scA  = scp[0];                              // group(1) == 0
    stage_a(0, 0);
    stage_b(pv00, pv01, sc0, lds_b + nb * BK);
    asm volatile("s_waitcnt lgkmcnt(0)" ::: "memory");
    __builtin_amdgcn_s_barrier();                        // publish bufB0 (DMA0 stays in flight)

    uint32_t pvB0 = 0, pvB1 = 0; float scB = 0.f;

    for (int t = 0; t < NSLAB; ++t) {
        const int cur = t & 1;

        if (t + 2 < NSLAB) {                              // operand prefetch (slab t+2)
            pvB0 = (uint32_t)pwp[(size_t)((t + 2) * 4 + 0) * N_DIM];
            pvB1 = (uint32_t)pwp[(size_t)((t + 2) * 4 + 1) * N_DIM];
            scB  = scp[(size_t)((t + 2) >> 1) * N_DIM];
        }
        if (t + 1 < NSLAB) {
            stage_a(t + 1, cur ^ 1);                      // 8 async DMAs, counted below
            stage_b(pvA0, pvA1, scA, lds_b + (cur ^ 1) * BBUF + nb * BK);
        }

        // wait own DMA(t) only; DMA(t+1)+prefetch loads stay in flight (T4)
        if (t + 2 < NSLAB)      asm volatile("s_waitcnt vmcnt(11)" ::: "memory");
        else if (t + 1 < NSLAB) asm volatile("s_waitcnt vmcnt(8)"  ::: "memory");
        else                    asm volatile("s_waitcnt vmcnt(0)"  ::: "memory");

        const _Float16* Ab = lds_a + cur * ABUF;
        const _Float16* Bb = lds_b + cur * BBUF;
        __builtin_amdgcn_s_setprio(1);
        #pragma unroll
        for (int h = 0; h < 2; ++h) {
            const int co = ((h * 4 + g) ^ x7) * 8;
            half8 af[4], bf[8];
            #pragma unroll
            for (int mt = 0; mt < 4; ++mt) af[mt] = *(const half8*)&Ab[aoff[mt] + co];
            #pragma unroll
            for (int nt = 0; nt < 8; ++nt) bf[nt] = *(const half8*)&Bb[boff[nt] + co];
            #pragma unroll
            for (int mt = 0; mt < 4; ++mt)
                #pragma unroll
                for (int nt = 0; nt < 8; ++nt)
                    acc[mt][nt] = __builtin_amdgcn_mfma_f32_16x16x32_f16(
                        af[mt], bf[nt], acc[mt][nt], 0, 0, 0);
        }
        __builtin_amdgcn_s_setprio(0);

        if (t + 1 < NSLAB) {
            // drain own ds ops (reads consumed + B writes), then publish; no vmcnt drain
            asm volatile("s_waitcnt lgkmcnt(0)" ::: "memory");
            __builtin_amdgcn_s_barrier();
        }
        pvA0 = pvB0; pvA1 = pvB1; scA = scB;
    }

    // ---- epilogue: fp32 acc + fp32 bias, stored unrounded (validated numerics) ----
    float bv[8];
    #pragma unroll
    for (int nt = 0; nt < 8; ++nt) bv[nt] = bias[n0 + wn + nt * 16 + lr];

    const int rbase = g * 4;          // C layout: row = (lane>>4)*4 + reg
    #pragma unroll
    for (int mt = 0; mt < 4; ++mt) {
        #pragma unroll
        for (int nt = 0; nt < 8; ++nt) {
            const int col = n0 + wn + nt * 16 + lr;
            float* op = out + (size_t)(m0 + band + mt * 16 + rbase) * N_DIM + col;
            floatx4 a = acc[mt][nt];
            #pragma unroll
            for (int r = 0; r < 4; ++r)
                op[(size_t)r * N_DIM] = a[r] + bv[nt];
        }
    }
}

// ---------------- fallback: round-0 validated kernel (used if ws too small) ------------
__global__ __launch_bounds__(256, 2) void ternary_gemm(
    const float* __restrict__ x,
    const int*   __restrict__ pw,
    const float* __restrict__ scales,
    const float* __restrict__ bias,
    float*       __restrict__ out)
{
    __shared__ __align__(16) _Float16 lds_a[FBM * FASTRIDE];
    __shared__ __align__(16) _Float16 lds_b[FBM * FBSTRIDE];

    const int tid  = threadIdx.x;
    const int lane = tid & 63;
    const int wave = tid >> 6;

    const int n0 = blockIdx.x * FBM;
    const int m0 = blockIdx.y * FBM;

    const int wm = (wave & 1) * 64;
    const int wn = (wave >> 1) * 64;

    const int nb  = tid & 127;
    const int kpi = tid >> 7;
    const int*   pwp = pw + (size_t)kpi * N_DIM + n0 + nb;
    const float* scp = scales + n0 + nb;
    _Float16* bl = lds_b + nb * FBSTRIDE + kpi * 16;

    floatx4 acc[4][4];
    #pragma unroll
    for (int i = 0; i < 4; ++i)
        #pragma unroll
        for (int j = 0; j < 4; ++j)
            acc[i][j] = floatx4{0.f, 0.f, 0.f, 0.f};

    const int lr = lane & 15;
    const int qk = (lane >> 4) * 8;

    for (int slab = 0; slab < K_DIM / FBK; ++slab) {
        const int k0 = slab * FBK;

        #pragma unroll
        for (int i = 0; i < 4; ++i) {
            const int idx = tid + i * 256;
            const int row = idx >> 3;
            const int kq  = (idx & 7) * 4;
            float4 v4 = *(const float4*)(x + (size_t)(m0 + row) * K_DIM + k0 + kq);
            half2v h0; h0[0] = (_Float16)v4.x; h0[1] = (_Float16)v4.y;
            half2v h1; h1[0] = (_Float16)v4.z; h1[1] = (_Float16)v4.w;
            *(uint2*)(lds_a + row * FASTRIDE + kq) =
                make_uint2(__builtin_bit_cast(uint32_t, h0),
                           __builtin_bit_cast(uint32_t, h1));
        }

        uint32_t v  = (uint32_t)pwp[(size_t)slab * 2 * N_DIM];
        _Float16 sh = (_Float16)scp[(size_t)(slab >> 2) * N_DIM];
        uint32_t sbits = (uint32_t)__builtin_bit_cast(unsigned short, sh);
        uint32_t tmpl = sbits | (((sbits >> 8) ^ 0x80u) << 24);

        uint32_t q[8];
        #pragma unroll
        for (int j = 0; j < 8; ++j) {
            uint32_t t4 = (v >> (4 * j)) & 0xFu;
            uint32_t sp = (t4 | (t4 << 14)) & 0x00030003u;
            uint32_t sel = ((sp & 0x00010001u) << 1) | ((0x00030003u - sp) << 8);
            q[j] = __builtin_amdgcn_perm(tmpl, tmpl, sel);
        }
        *(uint4*)(bl)     = make_uint4(q[0], q[1], q[2], q[3]);
        *(uint4*)(bl + 8) = make_uint4(q[4], q[5], q[6], q[7]);

        __syncthreads();

        half8 af[4], bfr[4];
        #pragma unroll
        for (int t = 0; t < 4; ++t) {
            af[t]  = *(const half8*)&lds_a[(wm + t * 16 + lr) * FASTRIDE + qk];
            bfr[t] = *(const half8*)&lds_b[(wn + t * 16 + lr) * FBSTRIDE + qk];
        }
        #pragma unroll
        for (int mt = 0; mt < 4; ++mt)
            #pragma unroll
            for (int nt = 0; nt < 4; ++nt)
                acc[mt][nt] = __builtin_amdgcn_mfma_f32_16x16x32_f16(
                    af[mt], bfr[nt], acc[mt][nt], 0, 0, 0);

        __syncthreads();
    }

    float bv[4];
    #pragma unroll
    for (int nt = 0; nt < 4; ++nt) bv[nt] = bias[n0 + wn + nt * 16 + lr];

    const int rbase = (lane >> 4) * 4;
    #pragma unroll
    for (int mt = 0; mt < 4; ++mt) {
        #pragma unroll
        for (int nt = 0; nt < 4; ++nt) {
            const int col = n0 + wn + nt * 16 + lr;
            float* op = out + (size_t)(m0 + wm + mt * 16 + rbase) * N_DIM + col;
            floatx4 a = acc[mt][nt];
            #pragma unroll
            for (int r = 0; r < 4; ++r)
                op[(size_t)r * N_DIM] = a[r] + bv[nt];
        }
    }
}

extern "C" void kernel_launch(void* const* d_in, const int* in_sizes, int n_in,
                              void* d_out, int out_size, void* d_ws, size_t ws_size,
                              hipStream_t stream) {
    const float* x  = (const float*)d_in[0];
    const int*   pw = (const int*)d_in[1];
    const float* sc = (const float*)d_in[2];
    const float* bs = (const float*)d_in[3];
    float* out = (float*)d_out;

    if (d_ws != nullptr && ws_size >= WS_NEEDED) {
        _Float16* xh = (_Float16*)d_ws;
        cvt_a<<<dim3((unsigned)((size_t)M_DIM * K_DIM / (256 * 8))), 256, 0, stream>>>(x, xh);
        ternary_gemm_db<<<dim3(NWG), 512, 0, stream>>>(xh, pw, sc, bs, out);
    } else {
        ternary_gemm<<<dim3(N_DIM / FBM, M_DIM / FBM), 256, 0, stream>>>(x, pw, sc, bs, out);
    }
}